// Round 1
// baseline (354.144 us; speedup 1.0000x reference)
//
#include <hip/hip_runtime.h>
#include <cstddef>
#include <cstdint>

#define D_MODEL 1024
#define D_STATE 8
#define D_INNER 1536
#define SEQ_L   2048
#define BATCH   4
#define MROWS   (BATCH * SEQ_L)   // 8192

// chunked scan: 16 chunks of 128, warmup 128 (|decay|<=0.55 -> err ~1e-32)
#define SCAN_CL 128
#define SCAN_W  128
#define SCAN_C  (SEQ_L / SCAN_CL)   // 16

typedef __attribute__((ext_vector_type(8))) short short8;
typedef __attribute__((ext_vector_type(4))) float f32x4;
typedef unsigned int u32;
typedef unsigned short u16;

__device__ __forceinline__ u16 bf_hi(float x) {            // truncate fp32 -> bf16
  return (u16)(__float_as_uint(x) >> 16);
}
__device__ __forceinline__ float bf_f(u16 h) {
  return __uint_as_float(((u32)h) << 16);
}
__device__ __forceinline__ void gload16(const void* g, void* l) {
  __builtin_amdgcn_global_load_lds((const __attribute__((address_space(1))) u32*)g,
                                   (__attribute__((address_space(3))) u32*)l, 16, 0, 0);
}

#define LGKM0()  asm volatile("s_waitcnt lgkmcnt(0)" ::: "memory")
#define VMCNT4() asm volatile("s_waitcnt vmcnt(4)" ::: "memory")
#define BARRIER()                                    \
  {                                                  \
    asm volatile("" ::: "memory");                   \
    __builtin_amdgcn_s_barrier();                    \
    asm volatile("" ::: "memory");                   \
  }

// ---------------------------------------------------------------- LayerNorm
// Plain fp32-out variant (used for LN-out -> d_out).
__global__ __launch_bounds__(256) void ln_kernel(
    const float* __restrict__ x, const float* __restrict__ g,
    const float* __restrict__ b, float* __restrict__ y)
{
  const int row = blockIdx.x;
  const int t = threadIdx.x;
  float4 v = reinterpret_cast<const float4*>(x + (size_t)row * D_MODEL)[t];
  float s  = v.x + v.y + v.z + v.w;
  float s2 = v.x * v.x + v.y * v.y + v.z * v.z + v.w * v.w;
  #pragma unroll
  for (int o = 32; o > 0; o >>= 1) {
    s  += __shfl_down(s, o);
    s2 += __shfl_down(s2, o);
  }
  __shared__ float ls[4], ls2[4];
  const int wid = t >> 6, lid = t & 63;
  if (lid == 0) { ls[wid] = s; ls2[wid] = s2; }
  __syncthreads();
  if (t == 0) {
    ls[0]  = ls[0] + ls[1] + ls[2] + ls[3];
    ls2[0] = ls2[0] + ls2[1] + ls2[2] + ls2[3];
  }
  __syncthreads();
  const float mean = ls[0] * (1.0f / D_MODEL);
  const float var  = ls2[0] * (1.0f / D_MODEL) - mean * mean;
  const float rstd = rsqrtf(var + 1e-5f);
  float4 gv = reinterpret_cast<const float4*>(g)[t];
  float4 bv = reinterpret_cast<const float4*>(b)[t];
  float4 o;
  o.x = (v.x - mean) * rstd * gv.x + bv.x;
  o.y = (v.y - mean) * rstd * gv.y + bv.y;
  o.z = (v.z - mean) * rstd * gv.z + bv.z;
  o.w = (v.w - mean) * rstd * gv.w + bv.w;
  reinterpret_cast<float4*>(y + (size_t)row * D_MODEL)[t] = o;
}

// LN-in variant: writes 2-term bf16 split planes (feeds GEMM1 directly).
__global__ __launch_bounds__(256) void ln_split_kernel(
    const float* __restrict__ x, const float* __restrict__ g,
    const float* __restrict__ b, u16* __restrict__ y0, u16* __restrict__ y1)
{
  const int row = blockIdx.x;
  const int t = threadIdx.x;
  float4 v = reinterpret_cast<const float4*>(x + (size_t)row * D_MODEL)[t];
  float s  = v.x + v.y + v.z + v.w;
  float s2 = v.x * v.x + v.y * v.y + v.z * v.z + v.w * v.w;
  #pragma unroll
  for (int o = 32; o > 0; o >>= 1) {
    s  += __shfl_down(s, o);
    s2 += __shfl_down(s2, o);
  }
  __shared__ float ls[4], ls2[4];
  const int wid = t >> 6, lid = t & 63;
  if (lid == 0) { ls[wid] = s; ls2[wid] = s2; }
  __syncthreads();
  if (t == 0) {
    ls[0]  = ls[0] + ls[1] + ls[2] + ls[3];
    ls2[0] = ls2[0] + ls2[1] + ls2[2] + ls2[3];
  }
  __syncthreads();
  const float mean = ls[0] * (1.0f / D_MODEL);
  const float var  = ls2[0] * (1.0f / D_MODEL) - mean * mean;
  const float rstd = rsqrtf(var + 1e-5f);
  float4 gv = reinterpret_cast<const float4*>(g)[t];
  float4 bv = reinterpret_cast<const float4*>(b)[t];
  float o[4];
  o[0] = (v.x - mean) * rstd * gv.x + bv.x;
  o[1] = (v.y - mean) * rstd * gv.y + bv.y;
  o[2] = (v.z - mean) * rstd * gv.z + bv.z;
  o[3] = (v.w - mean) * rstd * gv.w + bv.w;
  ushort4 h0, h1;
  u16 a, c;
  a = bf_hi(o[0]); c = bf_hi(o[0] - bf_f(a)); h0.x = a; h1.x = c;
  a = bf_hi(o[1]); c = bf_hi(o[1] - bf_f(a)); h0.y = a; h1.y = c;
  a = bf_hi(o[2]); c = bf_hi(o[2] - bf_f(a)); h0.z = a; h1.z = c;
  a = bf_hi(o[3]); c = bf_hi(o[3] - bf_f(a)); h0.w = a; h1.w = c;
  reinterpret_cast<ushort4*>(y0 + (size_t)row * D_MODEL)[t] = h0;
  reinterpret_cast<ushort4*>(y1 + (size_t)row * D_MODEL)[t] = h1;
}

// ------------------------------------------------- weight split kernel
// One launch handles both W_in (n1 elems -> a0/a1) and W_out (-> c0/c1).
__global__ __launch_bounds__(256) void wsplit_kernel(
    const float* __restrict__ W1, u16* __restrict__ a0, u16* __restrict__ a1,
    int n1, const float* __restrict__ W2, u16* __restrict__ c0,
    u16* __restrict__ c1, int n2)
{
  int i = blockIdx.x * 256 + threadIdx.x;
  if (i < n1) {
    float x = W1[i];
    u16 h0 = bf_hi(x);
    a0[i] = h0; a1[i] = bf_hi(x - bf_f(h0));
  } else if (i < n1 + n2) {
    int j = i - n1;
    float x = W2[j];
    u16 h0 = bf_hi(x);
    c0[j] = h0; c1[j] = bf_hi(x - bf_f(h0));
  }
}

// ---------------------------------------------------------------- GEMM
// out = clip(A @ B^T), A/B as 2-term bf16 splits.
//
// NEW structure (this round): phase-pipelined 256x128 tile, 8 waves
// (4M x 2N, per-wave 64x64), double-buffered LDS with counted vmcnt
// (T3+T4), st-style 8-chunk XOR swizzle (T2), setprio around MFMA
// clusters (T5). Raw s_barrier — NO __syncthreads -> no vmcnt(0) drain
// in the main loop.
//
// 1-combo (THREE=false): BK=64, pure bf16 a0b0. Per K-tile: 2 phases x
//   16 MFMA.  LDS row = 64 u16 = 8 chunks of 16B, chunks hold kslices
//   {0..31}{32..63}.
// 3-combo (THREE=true): BK=32, a0b0+a0b1+a1b0. Per K-tile: 2 phases x
//   24 MFMA.  Same physical LDS layout: chunks 0-3 hold plane-0 k0..31,
//   chunks 4-7 hold plane-1 k0..31 (two planes packed per 128B row so
//   the same 8-chunk XOR swizzle applies -> conflict-free reads).
//
// Swizzle: physical chunk = logical chunk ^ (row & 7). global_load_lds
// writes linearly (wave-uniform base + lane*16B), so the swizzle is
// applied by permuting the per-lane GLOBAL source address (m173
// pattern); ds_read applies the same XOR.
//
// Stage schedule (per thread: A* = 4 gloads, B* = 2 gloads):
//   P1: read A frags(8) + B-N0 frags(4); issue B*(k+1)   [B slots of
//       buffer (k+1)&1 freed at end of iter k-1 P2]
//   P2: read B-N1 frags(4); issue A*(k+2)                [A slots of
//       current buffer freed at end of P1]
//   vmcnt(4) before the P2 end-barrier: the 4 newest in-flight loads
//   are A*(k+2); everything tile k+1 needs is complete. Never 0.
template<bool THREE>
__device__ __forceinline__ void gemm_body(
    const u16* __restrict__ A0, const u16* __restrict__ A1,
    const u16* __restrict__ B0, const u16* __restrict__ B1,
    float* __restrict__ out0, float* __restrict__ out1,
    int K, int split, int ld0, int ld1, int m0, int n0, u16* sm)
{
  const int t = threadIdx.x;
  const int w = t >> 6, l = t & 63;
  const int wr = w >> 1, wc = w & 1;          // 4M x 2N waves
  const int q = l >> 4, m16 = l & 15;
  const int KSTEP = THREE ? 32 : 64;
  const int NK = K / KSTEP;

  // staging lane geometry: each wave covers 8 rows x 128B per gload16
  const int arow = l >> 3;                    // 0..7
  const int ac = l & 7;
  const int wrow8 = w * 8;

  auto stageA = [&](int kt) {                 // 256 rows, 4 gloads/thread
    const int kk = kt * KSTEP;
    u16* dst = sm + (size_t)(kt & 1) * 24576 + wrow8 * 64;
    #pragma unroll
    for (int jj = 0; jj < 4; jj++) {
      const int r = jj * 64 + wrow8 + arow;
      const int lc = ac ^ (r & 7);            // logical chunk for this slot
      const u16* src = THREE ? ((lc < 4) ? A0 : A1) : A0;
      const int col = kk + ((THREE ? (lc & 3) : lc) << 3);
      gload16(src + (size_t)(m0 + r) * K + col, dst + jj * 4096);
    }
  };
  auto stageB = [&](int kt) {                 // 128 rows, 2 gloads/thread
    const int kk = kt * KSTEP;
    u16* dst = sm + (size_t)(kt & 1) * 24576 + 16384 + wrow8 * 64;
    #pragma unroll
    for (int j = 0; j < 2; j++) {
      const int r = j * 64 + wrow8 + arow;
      const int lc = ac ^ (r & 7);
      const u16* src = THREE ? ((lc < 4) ? B0 : B1) : B0;
      const int col = kk + ((THREE ? (lc & 3) : lc) << 3);
      gload16(src + (size_t)(n0 + r) * K + col, dst + j * 4096);
    }
  };

  f32x4 acc[4][4];
  #pragma unroll
  for (int i = 0; i < 4; i++)
    #pragma unroll
    for (int j = 0; j < 4; j++) acc[i][j] = (f32x4)(0.0f);

  // prologue: A(0)[4] B(0)[2] A(1)[4]; vmcnt(4) -> tile 0 resident.
  stageA(0);
  stageB(0);
  stageA(1);
  VMCNT4();
  BARRIER();

  for (int k = 0; k < NK; ++k) {
    const u16* sA = sm + (size_t)(k & 1) * 24576;
    const u16* sB = sA + 16384;
    short8 a8[4][2], b8[4][2];

    // ---------------- phase 1: Q(N0) ----------------
    #pragma unroll
    for (int mt = 0; mt < 4; mt++) {
      const int r = wr * 64 + mt * 16 + m16;
      const int rb = r * 64;
      a8[mt][0] = *reinterpret_cast<const short8*>(sA + rb + ((q ^ (r & 7)) << 3));
      a8[mt][1] = *reinterpret_cast<const short8*>(sA + rb + (((4 + q) ^ (r & 7)) << 3));
    }
    #pragma unroll
    for (int nt = 0; nt < 2; nt++) {
      const int r = wc * 64 + nt * 16 + m16;
      const int rb = r * 64;
      b8[nt][0] = *reinterpret_cast<const short8*>(sB + rb + ((q ^ (r & 7)) << 3));
      b8[nt][1] = *reinterpret_cast<const short8*>(sB + rb + (((4 + q) ^ (r & 7)) << 3));
    }
    if (k + 1 < NK) stageB(k + 1);
    BARRIER();
    LGKM0();
    __builtin_amdgcn_s_setprio(1);
    #pragma unroll
    for (int mt = 0; mt < 4; mt++)
      #pragma unroll
      for (int nt = 0; nt < 2; nt++) {
        acc[mt][nt] = __builtin_amdgcn_mfma_f32_16x16x32_bf16(
            a8[mt][0], b8[nt][0], acc[mt][nt], 0, 0, 0);
        if (THREE) {
          acc[mt][nt] = __builtin_amdgcn_mfma_f32_16x16x32_bf16(
              a8[mt][0], b8[nt][1], acc[mt][nt], 0, 0, 0);
          acc[mt][nt] = __builtin_amdgcn_mfma_f32_16x16x32_bf16(
              a8[mt][1], b8[nt][0], acc[mt][nt], 0, 0, 0);
        } else {
          acc[mt][nt] = __builtin_amdgcn_mfma_f32_16x16x32_bf16(
              a8[mt][1], b8[nt][1], acc[mt][nt], 0, 0, 0);
        }
      }
    __builtin_amdgcn_s_setprio(0);
    BARRIER();

    // ---------------- phase 2: Q(N1) ----------------
    #pragma unroll
    for (int nt = 2; nt < 4; nt++) {
      const int r = wc * 64 + nt * 16 + m16;
      const int rb = r * 64;
      b8[nt][0] = *reinterpret_cast<const short8*>(sB + rb + ((q ^ (r & 7)) << 3));
      b8[nt][1] = *reinterpret_cast<const short8*>(sB + rb + (((4 + q) ^ (r & 7)) << 3));
    }
    if (k + 2 < NK) stageA(k + 2);
    BARRIER();
    LGKM0();
    __builtin_amdgcn_s_setprio(1);
    #pragma unroll
    for (int mt = 0; mt < 4; mt++)
      #pragma unroll
      for (int nt = 2; nt < 4; nt++) {
        acc[mt][nt] = __builtin_amdgcn_mfma_f32_16x16x32_bf16(
            a8[mt][0], b8[nt][0], acc[mt][nt], 0, 0, 0);
        if (THREE) {
          acc[mt][nt] = __builtin_amdgcn_mfma_f32_16x16x32_bf16(
              a8[mt][0], b8[nt][1], acc[mt][nt], 0, 0, 0);
          acc[mt][nt] = __builtin_amdgcn_mfma_f32_16x16x32_bf16(
              a8[mt][1], b8[nt][0], acc[mt][nt], 0, 0, 0);
        } else {
          acc[mt][nt] = __builtin_amdgcn_mfma_f32_16x16x32_bf16(
              a8[mt][1], b8[nt][1], acc[mt][nt], 0, 0, 0);
        }
      }
    __builtin_amdgcn_s_setprio(0);
    VMCNT4();                               // counted: next-tile resident,
    BARRIER();                              // A(k+2) still in flight
  }

  // epilogue: C/D layout col=lane&15, row=(lane>>4)*4+reg
  #pragma unroll
  for (int mt = 0; mt < 4; mt++) {
    #pragma unroll
    for (int nt = 0; nt < 4; nt++) {
      const int col = n0 + wc * 64 + nt * 16 + m16;
      #pragma unroll
      for (int r = 0; r < 4; r++) {
        const int row = m0 + wr * 64 + mt * 16 + q * 4 + r;
        float v = fminf(fmaxf(acc[mt][nt][r], -5.0f), 5.0f);
        if (col < split) out0[(size_t)row * ld0 + col] = v;
        else             out1[(size_t)row * ld1 + (col - split)] = v;
      }
    }
  }
}

__global__ __launch_bounds__(512, 2) void gemm_kernel(
    const u16* __restrict__ A0, const u16* __restrict__ A1,
    const u16* __restrict__ B0, const u16* __restrict__ B1,
    float* __restrict__ out0, float* __restrict__ out1,
    int K, int split, int ld0, int ld1, int lowprec_cols)
{
  __shared__ u16 sm[2][24576];               // 96 KiB: [A 256x64 | B 128x64] x2
  const int m0 = blockIdx.x * 256;
  // heavy-first: reverse N so 3-combo blocks dispatch before 1-combo
  const int nblk = (int)gridDim.y - 1 - (int)blockIdx.y;
  const int n0 = nblk * 128;
  if (n0 + 128 > lowprec_cols)
    gemm_body<true>(A0, A1, B0, B1, out0, out1, K, split, ld0, ld1, m0, n0,
                    &sm[0][0]);
  else
    gemm_body<false>(A0, A1, B0, B1, out0, out1, K, split, ld0, ld1, m0, n0,
                     &sm[0][0]);
}

// --------------------------------------------------------------- SSM scan
// Chunked: one thread per (chunk, b, i); warmup from h=0 (contraction,
// |decay| <= ~0.55 -> warmup error ~1e-32). Chunk 0 exact.
__global__ __launch_bounds__(256) void scan_kernel(
    const float* __restrict__ xssm, const float* __restrict__ gate,
    const float* __restrict__ A_log, const float* __restrict__ Bv,
    const float* __restrict__ Cv, u16* __restrict__ P0, u16* __restrict__ P1)
{
  const int gid = blockIdx.x * 256 + threadIdx.x;       // 0 .. 98303
  const int chunk = gid / (BATCH * D_INNER);            // 0..15
  const int rem = gid - chunk * (BATCH * D_INNER);
  const int b = rem / D_INNER;
  const int i = rem - b * D_INNER;

  float dec[D_STATE], bb[D_STATE], cc[D_STATE], h[D_STATE];
  #pragma unroll
  for (int s = 0; s < D_STATE; s++) {
    float al = A_log[i * D_STATE + s];
    al = fminf(fmaxf(al, -5.0f), 0.0f);
    float a = -__expf(al);
    a = fminf(fmaxf(a, -2.0f), -0.01f);
    dec[s] = a * 0.9f;
    bb[s]  = Bv[i * D_STATE + s] * 0.1f;
    cc[s]  = Cv[i * D_STATE + s];
    h[s]   = 0.0f;
  }

  const size_t base = (size_t)b * SEQ_L * D_INNER + i;
  const int tmain = chunk * SCAN_CL;
  const int tw = (tmain >= SCAN_W) ? (tmain - SCAN_W) : 0;

  for (int t0 = tw; t0 < tmain; t0 += 16) {
    float xv[16];
    #pragma unroll
    for (int j = 0; j < 16; j++)
      xv[j] = xssm[base + (size_t)(t0 + j) * D_INNER];
    #pragma unroll
    for (int j = 0; j < 16; j++) {
      const float x = xv[j];
      #pragma unroll
      for (int s = 0; s < D_STATE; s++) {
        h[s] = fmaf(h[s], dec[s], x * bb[s]);
        h[s] = fminf(fmaxf(h[s], -5.0f), 5.0f);
      }
    }
  }

  float xf[8], gf[8];
  #pragma unroll
  for (int j = 0; j < 8; j++) {
    xf[j] = xssm[base + (size_t)(tmain + j) * D_INNER];
    gf[j] = gate[base + (size_t)(tmain + j) * D_INNER];
  }
  for (int t0 = tmain; t0 < tmain + SCAN_CL; t0 += 8) {
    float xn[8], gn[8];
    if (t0 + 8 < tmain + SCAN_CL) {
      #pragma unroll
      for (int j = 0; j < 8; j++) {
        xn[j] = xssm[base + (size_t)(t0 + 8 + j) * D_INNER];
        gn[j] = gate[base + (size_t)(t0 + 8 + j) * D_INNER];
      }
    }
    #pragma unroll
    for (int j = 0; j < 8; j++) {
      const float x = xf[j];
      float y = 0.0f;
      #pragma unroll
      for (int s = 0; s < D_STATE; s++) {
        h[s] = fmaf(h[s], dec[s], x * bb[s]);
        h[s] = fminf(fmaxf(h[s], -5.0f), 5.0f);
        y = fmaf(h[s], cc[s], y);
      }
      y = fminf(fmaxf(y, -5.0f), 5.0f);
      const float e  = __expf(2.0f * gf[j]);
      const float th = __fdividef(e - 1.0f, e + 1.0f);
      const float p = y * th;
      const u16 h0 = bf_hi(p);
      const u16 h1 = bf_hi(p - bf_f(h0));
      P0[base + (size_t)(t0 + j) * D_INNER] = h0;
      P1[base + (size_t)(t0 + j) * D_INNER] = h1;
    }
    #pragma unroll
    for (int j = 0; j < 8; j++) { xf[j] = xn[j]; gf[j] = gn[j]; }
  }
}

// ---------------------------------------------------------------- launcher
extern "C" void kernel_launch(void* const* d_in, const int* in_sizes, int n_in,
                              void* d_out, int out_size, void* d_ws, size_t ws_size,
                              hipStream_t stream)
{
  const float* x        = (const float*)d_in[0];
  const float* W_in     = (const float*)d_in[1];
  const float* W_out    = (const float*)d_in[2];
  const float* A_log    = (const float*)d_in[3];
  const float* Bmat     = (const float*)d_in[4];
  const float* Cmat     = (const float*)d_in[5];
  const float* ln_in_g  = (const float*)d_in[6];
  const float* ln_in_b  = (const float*)d_in[7];
  const float* ln_out_g = (const float*)d_in[8];
  const float* ln_out_b = (const float*)d_in[9];
  float* out = (float*)d_out;

  // workspace (bytes):
  // [xssm 50331648][gate 50331648][xn0 16777216][xn1 16777216][B0 6291456]
  // [B1 6291456][gap][V0 3145728][V1 3145728]  total 159,383,552
  // P0/P1 (2x25165824) overlay xn0/xn1/B0/B1 (dead after gemm1);
  // outp overlays xssm (dead after scan).
  char* ws = (char*)d_ws;
  float* xssm = (float*)(ws);
  float* gate = (float*)(ws + 50331648);
  u16* xn0 = (u16*)(ws + 100663296);
  u16* xn1 = (u16*)(ws + 117440512);
  u16* B0  = (u16*)(ws + 134217728);
  u16* B1  = (u16*)(ws + 140509184);
  u16* V0  = (u16*)(ws + 153092096);
  u16* V1  = (u16*)(ws + 156237824);
  u16* P0  = (u16*)(ws + 100663296);
  u16* P1  = P0 + (size_t)MROWS * D_INNER;
  float* outp = xssm;

  // 0) split both weight matrices into 2-term bf16 (single launch)
  {
    const int n1 = 2 * D_INNER * D_MODEL;      // W_in
    const int n2 = D_MODEL * D_INNER;          // W_out
    wsplit_kernel<<<(n1 + n2 + 255) / 256, 256, 0, stream>>>(
        W_in, B0, B1, n1, W_out, V0, V1, n2);
  }

  // 1) LayerNorm-in -> 2-term bf16 planes
  ln_split_kernel<<<MROWS, 256, 0, stream>>>(x, ln_in_g, ln_in_b, xn0, xn1);

  // 2) x_proj = clip(xn @ W_in^T), split-store xssm/gate.
  //    Columns < 1536 (x_ssm half) use 1-combo pure bf16 (scan attenuates
  //    their error ~1e-4x); gate half uses 3 combos.
  {
    dim3 grid(MROWS / 256, (2 * D_INNER) / 128);   // 32 x 24
    gemm_kernel<<<grid, 512, 0, stream>>>(xn0, xn1, B0, B1, xssm, gate,
                                          D_MODEL, D_INNER, D_INNER, D_INNER,
                                          D_INNER /* lowprec: x_ssm half */);
  }

  // 3) chunked SSM scan -> prod as 2-term bf16
  scan_kernel<<<(BATCH * D_INNER * SCAN_C) / 256, 256, 0, stream>>>(
      xssm, gate, A_log, Bmat, Cmat, P0, P1);

  // 4) out_pre = clip(prod @ W_out^T) — full 3-combo precision
  {
    dim3 grid(MROWS / 256, D_MODEL / 128);          // 32 x 8
    gemm_kernel<<<grid, 512, 0, stream>>>(P0, P1, V0, V1, outp, outp,
                                          D_INNER, D_MODEL, D_MODEL, D_MODEL,
                                          0 /* all high-precision */);
  }

  // 5) LayerNorm-out -> d_out
  ln_kernel<<<MROWS, 256, 0, stream>>>(outp, ln_out_g, ln_out_b, out);
}

// Round 2
// 340.236 us; speedup vs baseline: 1.0409x; 1.0409x over previous
//
#include <hip/hip_runtime.h>
#include <cstddef>
#include <cstdint>

#define D_MODEL 1024
#define D_STATE 8
#define D_INNER 1536
#define SEQ_L   2048
#define BATCH   4
#define MROWS   (BATCH * SEQ_L)   // 8192

// chunked scan: 16 chunks of 128, warmup 128 (|decay|<=0.55 -> err ~1e-32)
#define SCAN_CL 128
#define SCAN_W  128
#define SCAN_C  (SEQ_L / SCAN_CL)   // 16

typedef __attribute__((ext_vector_type(8))) short short8;
typedef __attribute__((ext_vector_type(4))) float f32x4;
typedef unsigned int u32;
typedef unsigned short u16;

__device__ __forceinline__ u16 bf_hi(float x) {            // truncate fp32 -> bf16
  return (u16)(__float_as_uint(x) >> 16);
}
__device__ __forceinline__ float bf_f(u16 h) {
  return __uint_as_float(((u32)h) << 16);
}
__device__ __forceinline__ void gload16(const void* g, void* l) {
  __builtin_amdgcn_global_load_lds((const __attribute__((address_space(1))) u32*)g,
                                   (__attribute__((address_space(3))) u32*)l, 16, 0, 0);
}

#define LGKM0()  asm volatile("s_waitcnt lgkmcnt(0)" ::: "memory")
#define VMCNT4() asm volatile("s_waitcnt vmcnt(4)" ::: "memory")
#define VMCNT0() asm volatile("s_waitcnt vmcnt(0)" ::: "memory")
#define BARRIER()                                    \
  {                                                  \
    asm volatile("" ::: "memory");                   \
    __builtin_amdgcn_s_barrier();                    \
    asm volatile("" ::: "memory");                   \
  }

// ---------------------------------------------------------------- LayerNorm
__global__ __launch_bounds__(256) void ln_split_kernel(
    const float* __restrict__ x, const float* __restrict__ g,
    const float* __restrict__ b, u16* __restrict__ y0, u16* __restrict__ y1)
{
  const int row = blockIdx.x;
  const int t = threadIdx.x;
  float4 v = reinterpret_cast<const float4*>(x + (size_t)row * D_MODEL)[t];
  float s  = v.x + v.y + v.z + v.w;
  float s2 = v.x * v.x + v.y * v.y + v.z * v.z + v.w * v.w;
  #pragma unroll
  for (int o = 32; o > 0; o >>= 1) {
    s  += __shfl_down(s, o);
    s2 += __shfl_down(s2, o);
  }
  __shared__ float ls[4], ls2[4];
  const int wid = t >> 6, lid = t & 63;
  if (lid == 0) { ls[wid] = s; ls2[wid] = s2; }
  __syncthreads();
  if (t == 0) {
    ls[0]  = ls[0] + ls[1] + ls[2] + ls[3];
    ls2[0] = ls2[0] + ls2[1] + ls2[2] + ls2[3];
  }
  __syncthreads();
  const float mean = ls[0] * (1.0f / D_MODEL);
  const float var  = ls2[0] * (1.0f / D_MODEL) - mean * mean;
  const float rstd = rsqrtf(var + 1e-5f);
  float4 gv = reinterpret_cast<const float4*>(g)[t];
  float4 bv = reinterpret_cast<const float4*>(b)[t];
  float o[4];
  o[0] = (v.x - mean) * rstd * gv.x + bv.x;
  o[1] = (v.y - mean) * rstd * gv.y + bv.y;
  o[2] = (v.z - mean) * rstd * gv.z + bv.z;
  o[3] = (v.w - mean) * rstd * gv.w + bv.w;
  ushort4 h0, h1;
  u16 a, c;
  a = bf_hi(o[0]); c = bf_hi(o[0] - bf_f(a)); h0.x = a; h1.x = c;
  a = bf_hi(o[1]); c = bf_hi(o[1] - bf_f(a)); h0.y = a; h1.y = c;
  a = bf_hi(o[2]); c = bf_hi(o[2] - bf_f(a)); h0.z = a; h1.z = c;
  a = bf_hi(o[3]); c = bf_hi(o[3] - bf_f(a)); h0.w = a; h1.w = c;
  reinterpret_cast<ushort4*>(y0 + (size_t)row * D_MODEL)[t] = h0;
  reinterpret_cast<ushort4*>(y1 + (size_t)row * D_MODEL)[t] = h1;
}

// LN over clip(pa+pb) — fuses GEMM2's split-K reduction + clip epilogue.
__global__ __launch_bounds__(256) void ln_sum_kernel(
    const float* __restrict__ xa, const float* __restrict__ xb,
    const float* __restrict__ g, const float* __restrict__ b,
    float* __restrict__ y)
{
  const int row = blockIdx.x;
  const int t = threadIdx.x;
  float4 va = reinterpret_cast<const float4*>(xa + (size_t)row * D_MODEL)[t];
  float4 vb = reinterpret_cast<const float4*>(xb + (size_t)row * D_MODEL)[t];
  float4 v;
  v.x = fminf(fmaxf(va.x + vb.x, -5.0f), 5.0f);
  v.y = fminf(fmaxf(va.y + vb.y, -5.0f), 5.0f);
  v.z = fminf(fmaxf(va.z + vb.z, -5.0f), 5.0f);
  v.w = fminf(fmaxf(va.w + vb.w, -5.0f), 5.0f);
  float s  = v.x + v.y + v.z + v.w;
  float s2 = v.x * v.x + v.y * v.y + v.z * v.z + v.w * v.w;
  #pragma unroll
  for (int o = 32; o > 0; o >>= 1) {
    s  += __shfl_down(s, o);
    s2 += __shfl_down(s2, o);
  }
  __shared__ float ls[4], ls2[4];
  const int wid = t >> 6, lid = t & 63;
  if (lid == 0) { ls[wid] = s; ls2[wid] = s2; }
  __syncthreads();
  if (t == 0) {
    ls[0]  = ls[0] + ls[1] + ls[2] + ls[3];
    ls2[0] = ls2[0] + ls2[1] + ls2[2] + ls2[3];
  }
  __syncthreads();
  const float mean = ls[0] * (1.0f / D_MODEL);
  const float var  = ls2[0] * (1.0f / D_MODEL) - mean * mean;
  const float rstd = rsqrtf(var + 1e-5f);
  float4 gv = reinterpret_cast<const float4*>(g)[t];
  float4 bv = reinterpret_cast<const float4*>(b)[t];
  float4 o;
  o.x = (v.x - mean) * rstd * gv.x + bv.x;
  o.y = (v.y - mean) * rstd * gv.y + bv.y;
  o.z = (v.z - mean) * rstd * gv.z + bv.z;
  o.w = (v.w - mean) * rstd * gv.w + bv.w;
  reinterpret_cast<float4*>(y + (size_t)row * D_MODEL)[t] = o;
}

// ------------------------------------------------- weight split kernel
__global__ __launch_bounds__(256) void wsplit_kernel(
    const float* __restrict__ W1, u16* __restrict__ a0, u16* __restrict__ a1,
    int n1, const float* __restrict__ W2, u16* __restrict__ c0,
    u16* __restrict__ c1, int n2)
{
  int i = blockIdx.x * 256 + threadIdx.x;
  if (i < n1) {
    float x = W1[i];
    u16 h0 = bf_hi(x);
    a0[i] = h0; a1[i] = bf_hi(x - bf_f(h0));
  } else if (i < n1 + n2) {
    int j = i - n1;
    float x = W2[j];
    u16 h0 = bf_hi(x);
    c0[j] = h0; c1[j] = bf_hi(x - bf_f(h0));
  }
}

// ---------------------------------------------------------------- GEMM
// m201-fidelity 256x256 tile, 8 waves (2M x 4N, per-wave 128x64), BK=64
// (1-combo) / BK=32 packed-planes (3-combo).  4 quadrant phases per
// K-tile, 16 (or 24) MFMA each, double-buffered 128 KiB LDS, 8-chunk
// XOR swizzle (round-1 verified: 0 bank conflicts), counted vmcnt(4)
// twice per K-tile (never a full drain except the last tile), setprio
// around each MFMA cluster.
//
// Stage groups (16 KiB each, 2 gloads/thread), matched to phase needs:
//   Aalpha = rows bit6==0  (what mh0 quadrants read, across both wr)
//   Abeta  = rows bit6==1
//   Balpha = rows bit5==0  (what nh0 quadrants read, across all wc)
//   Bbeta  = rows bit5==1
// Issue schedule (tile k): ph1: Aalpha,Balpha(k+1); ph2: Abeta,Bbeta(k+1).
// Waits: ph1-end vmcnt(4) -> beta(k) resident (read ph2/ph3), alpha(k+1)
// stays in flight; ph4-end vmcnt(4) -> alpha(k+1) resident (read next
// ph1), beta(k+1) stays in flight.  Steady state: 4..8 loads in flight.
#define MFMA(a, b, c) __builtin_amdgcn_mfma_f32_16x16x32_bf16(a, b, c, 0, 0, 0)
#define LD8(base, rb, c) \
  (*reinterpret_cast<const short8*>((base) + (rb) + ((c) << 3)))

template<bool THREE>
__device__ __forceinline__ void gemm_body(
    const u16* __restrict__ A0, const u16* __restrict__ A1,
    const u16* __restrict__ B0, const u16* __restrict__ B1,
    float* __restrict__ out0, float* __restrict__ out1,
    int K, int Kld, int koff, int split, int ld0, int ld1,
    int m0, int n0, int doclip, u16* sm)
{
  const int t = threadIdx.x;
  const int w = t >> 6, l = t & 63;
  const int wr = w >> 2, wc = w & 3;          // 2M x 4N waves
  const int q = l >> 4, m16 = l & 15;
  constexpr int KSTEP = THREE ? 32 : 64;
  const int NK = K / KSTEP;

  // staging lane geometry: one gload = 8 rows x 128B, lane l covers
  // row l>>3, physical chunk l&7; logical chunk = (l&7) ^ (row&7).
  const int arow = l >> 3, ac = l & 7;
  const int lc = ac ^ arow;
  const int coff = THREE ? ((lc & 3) << 3) : (lc << 3);
  const u16* const Asrc = (THREE && (lc & 4)) ? A1 : A0;
  const u16* const Bsrc = (THREE && (lc & 4)) ? B1 : B0;

  auto stageA = [&](int kt, int half) {
    const int kk = kt * KSTEP + koff + coff;
    u16* dbuf = sm + (size_t)(kt & 1) * 32768;
    #pragma unroll
    for (int j = 0; j < 2; j++) {
      const int gi = (j * 8 + w) * 8 + arow;
      const int r = ((gi & 63) | ((gi >> 6) << 7)) + half * 64;
      gload16(Asrc + (size_t)(m0 + r) * Kld + kk, dbuf + (r & ~7) * 64);
    }
  };
  auto stageB = [&](int kt, int half) {
    const int kk = kt * KSTEP + koff + coff;
    u16* dbuf = sm + (size_t)(kt & 1) * 32768 + 16384;
    #pragma unroll
    for (int j = 0; j < 2; j++) {
      const int gi = (j * 8 + w) * 8 + arow;
      const int r = ((gi & 31) | ((gi >> 5) << 6)) + half * 32;
      gload16(Bsrc + (size_t)(n0 + r) * Kld + kk, dbuf + (r & ~7) * 64);
    }
  };

  f32x4 acc[8][4];
  #pragma unroll
  for (int i = 0; i < 8; i++)
    #pragma unroll
    for (int j = 0; j < 4; j++) acc[i][j] = (f32x4)(0.0f);

  // prologue: alpha(0), beta(0); vmcnt(4) -> alpha resident, beta in flight
  stageA(0, 0); stageB(0, 0);
  stageA(0, 1); stageB(0, 1);
  VMCNT4();
  BARRIER();

  short8 af[4][2], bf[4][2];

#define QUAD(mh, nh)                                                     \
  do {                                                                   \
    _Pragma("unroll")                                                    \
    for (int mt = 0; mt < 4; mt++) {                                     \
      _Pragma("unroll")                                                  \
      for (int nt = 0; nt < 2; nt++) {                                   \
        f32x4 c = acc[(mh) * 4 + mt][(nh) * 2 + nt];                     \
        if (THREE) {                                                     \
          c = MFMA(af[mt][0], bf[(nh) * 2 + nt][0], c);                  \
          c = MFMA(af[mt][0], bf[(nh) * 2 + nt][1], c);                  \
          c = MFMA(af[mt][1], bf[(nh) * 2 + nt][0], c);                  \
        } else {                                                         \
          c = MFMA(af[mt][0], bf[(nh) * 2 + nt][0], c);                  \
          c = MFMA(af[mt][1], bf[(nh) * 2 + nt][1], c);                  \
        }                                                                \
        acc[(mh) * 4 + mt][(nh) * 2 + nt] = c;                           \
      }                                                                  \
    }                                                                    \
  } while (0)

  for (int k = 0; k < NK; ++k) {
    const u16* sA = sm + (size_t)(k & 1) * 32768;
    const u16* sB = sA + 16384;
    const bool pf = (k + 1 < NK);

    // ---- phase 1: quadrant (mh0, nh0) ----
    #pragma unroll
    for (int mt = 0; mt < 4; mt++) {
      const int r = wr * 128 + mt * 16 + m16, rb = r * 64, rx = r & 7;
      af[mt][0] = LD8(sA, rb, q ^ rx);
      af[mt][1] = LD8(sA, rb, (4 + q) ^ rx);
    }
    #pragma unroll
    for (int nt = 0; nt < 2; nt++) {
      const int r = wc * 64 + nt * 16 + m16, rb = r * 64, rx = r & 7;
      bf[nt][0] = LD8(sB, rb, q ^ rx);
      bf[nt][1] = LD8(sB, rb, (4 + q) ^ rx);
    }
    if (pf) { stageA(k + 1, 0); stageB(k + 1, 0); }
    BARRIER();
    LGKM0();
    __builtin_amdgcn_s_setprio(1);
    QUAD(0, 0);
    __builtin_amdgcn_s_setprio(0);
    if (pf) VMCNT4(); else VMCNT0();   // beta(k) resident for ph2/ph3
    BARRIER();

    // ---- phase 2: quadrant (mh0, nh1) ----
    #pragma unroll
    for (int nt = 2; nt < 4; nt++) {
      const int r = wc * 64 + nt * 16 + m16, rb = r * 64, rx = r & 7;
      bf[nt][0] = LD8(sB, rb, q ^ rx);
      bf[nt][1] = LD8(sB, rb, (4 + q) ^ rx);
    }
    if (pf) { stageA(k + 1, 1); stageB(k + 1, 1); }
    BARRIER();
    LGKM0();
    __builtin_amdgcn_s_setprio(1);
    QUAD(0, 1);
    __builtin_amdgcn_s_setprio(0);
    BARRIER();

    // ---- phase 3: quadrant (mh1, nh0) ----
    #pragma unroll
    for (int mt = 0; mt < 4; mt++) {
      const int r = wr * 128 + 64 + mt * 16 + m16, rb = r * 64, rx = r & 7;
      af[mt][0] = LD8(sA, rb, q ^ rx);
      af[mt][1] = LD8(sA, rb, (4 + q) ^ rx);
    }
    BARRIER();
    LGKM0();
    __builtin_amdgcn_s_setprio(1);
    QUAD(1, 0);
    __builtin_amdgcn_s_setprio(0);
    BARRIER();

    // ---- phase 4: quadrant (mh1, nh1) ----
    __builtin_amdgcn_s_setprio(1);
    QUAD(1, 1);
    __builtin_amdgcn_s_setprio(0);
    if (pf) {
      VMCNT4();                        // alpha(k+1) resident for next ph1
      BARRIER();
    }
  }
#undef QUAD

  // epilogue: C/D layout col=lane&15, row=(lane>>4)*4+reg
  #pragma unroll
  for (int mt = 0; mt < 8; mt++) {
    #pragma unroll
    for (int nt = 0; nt < 4; nt++) {
      const int col = n0 + wc * 64 + nt * 16 + m16;
      #pragma unroll
      for (int r = 0; r < 4; r++) {
        const int row = m0 + wr * 128 + mt * 16 + q * 4 + r;
        float v = acc[mt][nt][r];
        if (doclip) v = fminf(fmaxf(v, -5.0f), 5.0f);
        if (col < split) out0[(size_t)row * ld0 + col] = v;
        else             out1[(size_t)row * ld1 + (col - split)] = v;
      }
    }
  }
}

// GEMM1: x_proj = clip(xn @ W_in^T); cols <1536 (x_ssm) 1-combo, rest 3-combo.
__global__ __launch_bounds__(512, 2) void gemm1_kernel(
    const u16* __restrict__ A0, const u16* __restrict__ A1,
    const u16* __restrict__ B0, const u16* __restrict__ B1,
    float* __restrict__ out0, float* __restrict__ out1)
{
  __shared__ u16 sm[2][32768];               // 128 KiB
  const int m0 = blockIdx.x * 256;
  const int nblk = (int)gridDim.y - 1 - (int)blockIdx.y;   // heavy-first
  const int n0 = nblk * 256;
  if (n0 >= D_INNER)
    gemm_body<true>(A0, A1, B0, B1, out0, out1, D_MODEL, D_MODEL, 0,
                    D_INNER, D_INNER, D_INNER, m0, n0, 1, &sm[0][0]);
  else
    gemm_body<false>(A0, A1, B0, B1, out0, out1, D_MODEL, D_MODEL, 0,
                     D_INNER, D_INNER, D_INNER, m0, n0, 1, &sm[0][0]);
}

// GEMM2: out_pre partials = prod @ W_out^T, split-K=2 (unclipped fp32
// partials into outA/outB; ln_sum does clip(pa+pb) + LN).
__global__ __launch_bounds__(512, 2) void gemm2_kernel(
    const u16* __restrict__ P0, const u16* __restrict__ P1,
    const u16* __restrict__ V0, const u16* __restrict__ V1,
    float* __restrict__ outA, float* __restrict__ outB)
{
  __shared__ u16 sm[2][32768];
  const int m0 = blockIdx.x * 256;
  const int by = (int)blockIdx.y;
  const int kslice = by >> 2;
  const int n0 = (by & 3) * 256;
  float* o = kslice ? outB : outA;
  gemm_body<true>(P0, P1, V0, V1, o, o, 768, 1536, kslice * 768,
                  D_MODEL, D_MODEL, D_MODEL, m0, n0, 0, &sm[0][0]);
}

// --------------------------------------------------------------- SSM scan
__global__ __launch_bounds__(256) void scan_kernel(
    const float* __restrict__ xssm, const float* __restrict__ gate,
    const float* __restrict__ A_log, const float* __restrict__ Bv,
    const float* __restrict__ Cv, u16* __restrict__ P0, u16* __restrict__ P1)
{
  const int gid = blockIdx.x * 256 + threadIdx.x;       // 0 .. 98303
  const int chunk = gid / (BATCH * D_INNER);            // 0..15
  const int rem = gid - chunk * (BATCH * D_INNER);
  const int b = rem / D_INNER;
  const int i = rem - b * D_INNER;

  float dec[D_STATE], bb[D_STATE], cc[D_STATE], h[D_STATE];
  #pragma unroll
  for (int s = 0; s < D_STATE; s++) {
    float al = A_log[i * D_STATE + s];
    al = fminf(fmaxf(al, -5.0f), 0.0f);
    float a = -__expf(al);
    a = fminf(fmaxf(a, -2.0f), -0.01f);
    dec[s] = a * 0.9f;
    bb[s]  = Bv[i * D_STATE + s] * 0.1f;
    cc[s]  = Cv[i * D_STATE + s];
    h[s]   = 0.0f;
  }

  const size_t base = (size_t)b * SEQ_L * D_INNER + i;
  const int tmain = chunk * SCAN_CL;
  const int tw = (tmain >= SCAN_W) ? (tmain - SCAN_W) : 0;

  for (int t0 = tw; t0 < tmain; t0 += 16) {
    float xv[16];
    #pragma unroll
    for (int j = 0; j < 16; j++)
      xv[j] = xssm[base + (size_t)(t0 + j) * D_INNER];
    #pragma unroll
    for (int j = 0; j < 16; j++) {
      const float x = xv[j];
      #pragma unroll
      for (int s = 0; s < D_STATE; s++) {
        h[s] = fmaf(h[s], dec[s], x * bb[s]);
        h[s] = fminf(fmaxf(h[s], -5.0f), 5.0f);
      }
    }
  }

  float xf[8], gf[8];
  #pragma unroll
  for (int j = 0; j < 8; j++) {
    xf[j] = xssm[base + (size_t)(tmain + j) * D_INNER];
    gf[j] = gate[base + (size_t)(tmain + j) * D_INNER];
  }
  for (int t0 = tmain; t0 < tmain + SCAN_CL; t0 += 8) {
    float xn[8], gn[8];
    if (t0 + 8 < tmain + SCAN_CL) {
      #pragma unroll
      for (int j = 0; j < 8; j++) {
        xn[j] = xssm[base + (size_t)(t0 + 8 + j) * D_INNER];
        gn[j] = gate[base + (size_t)(t0 + 8 + j) * D_INNER];
      }
    }
    #pragma unroll
    for (int j = 0; j < 8; j++) {
      const float x = xf[j];
      float y = 0.0f;
      #pragma unroll
      for (int s = 0; s < D_STATE; s++) {
        h[s] = fmaf(h[s], dec[s], x * bb[s]);
        h[s] = fminf(fmaxf(h[s], -5.0f), 5.0f);
        y = fmaf(h[s], cc[s], y);
      }
      y = fminf(fmaxf(y, -5.0f), 5.0f);
      const float e  = __expf(2.0f * gf[j]);
      const float th = __fdividef(e - 1.0f, e + 1.0f);
      const float p = y * th;
      const u16 h0 = bf_hi(p);
      const u16 h1 = bf_hi(p - bf_f(h0));
      P0[base + (size_t)(t0 + j) * D_INNER] = h0;
      P1[base + (size_t)(t0 + j) * D_INNER] = h1;
    }
    #pragma unroll
    for (int j = 0; j < 8; j++) { xf[j] = xn[j]; gf[j] = gn[j]; }
  }
}

// ---------------------------------------------------------------- launcher
extern "C" void kernel_launch(void* const* d_in, const int* in_sizes, int n_in,
                              void* d_out, int out_size, void* d_ws, size_t ws_size,
                              hipStream_t stream)
{
  const float* x        = (const float*)d_in[0];
  const float* W_in     = (const float*)d_in[1];
  const float* W_out    = (const float*)d_in[2];
  const float* A_log    = (const float*)d_in[3];
  const float* Bmat     = (const float*)d_in[4];
  const float* Cmat     = (const float*)d_in[5];
  const float* ln_in_g  = (const float*)d_in[6];
  const float* ln_in_b  = (const float*)d_in[7];
  const float* ln_out_g = (const float*)d_in[8];
  const float* ln_out_b = (const float*)d_in[9];
  float* out = (float*)d_out;

  // workspace (bytes):
  // [xssm 50331648][gate 50331648][xn0 16777216][xn1 16777216][B0 6291456]
  // [B1 6291456][gap][V0 3145728][V1 3145728]  total 159,383,552
  // P0/P1 (2x25165824) overlay xn0/xn1/B0/B1 (dead after gemm1);
  // GEMM2 partials: outA overlays xssm, outB overlays gate (dead after scan).
  char* ws = (char*)d_ws;
  float* xssm = (float*)(ws);
  float* gate = (float*)(ws + 50331648);
  u16* xn0 = (u16*)(ws + 100663296);
  u16* xn1 = (u16*)(ws + 117440512);
  u16* B0  = (u16*)(ws + 134217728);
  u16* B1  = (u16*)(ws + 140509184);
  u16* V0  = (u16*)(ws + 153092096);
  u16* V1  = (u16*)(ws + 156237824);
  u16* P0  = (u16*)(ws + 100663296);
  u16* P1  = P0 + (size_t)MROWS * D_INNER;
  float* outA = xssm;
  float* outB = gate;

  // 0) split both weight matrices into 2-term bf16 (single launch)
  {
    const int n1 = 2 * D_INNER * D_MODEL;      // W_in
    const int n2 = D_MODEL * D_INNER;          // W_out
    wsplit_kernel<<<(n1 + n2 + 255) / 256, 256, 0, stream>>>(
        W_in, B0, B1, n1, W_out, V0, V1, n2);
  }

  // 1) LayerNorm-in -> 2-term bf16 planes
  ln_split_kernel<<<MROWS, 256, 0, stream>>>(x, ln_in_g, ln_in_b, xn0, xn1);

  // 2) x_proj = clip(xn @ W_in^T), split-store xssm/gate.
  gemm1_kernel<<<dim3(MROWS / 256, (2 * D_INNER) / 256), 512, 0, stream>>>(
      xn0, xn1, B0, B1, xssm, gate);

  // 3) chunked SSM scan -> prod as 2-term bf16
  scan_kernel<<<(BATCH * D_INNER * SCAN_C) / 256, 256, 0, stream>>>(
      xssm, gate, A_log, Bmat, Cmat, P0, P1);

  // 4) out_pre = prod @ W_out^T, split-K=2 -> fp32 partials outA/outB
  gemm2_kernel<<<dim3(MROWS / 256, 2 * (D_MODEL / 256)), 512, 0, stream>>>(
      P0, P1, V0, V1, outA, outB);

  // 5) LayerNorm over clip(outA + outB) -> d_out
  ln_sum_kernel<<<MROWS, 256, 0, stream>>>(outA, outB, ln_out_g, ln_out_b, out);
}

// Round 3
// 324.975 us; speedup vs baseline: 1.0898x; 1.0470x over previous
//
#include <hip/hip_runtime.h>
#include <cstddef>
#include <cstdint>

#define D_MODEL 1024
#define D_STATE 8
#define D_INNER 1536
#define SEQ_L   2048
#define BATCH   4
#define MROWS   (BATCH * SEQ_L)   // 8192

// chunked scan: 16 chunks of 128, warmup 128 (|decay|<=0.55 -> err ~1e-32)
#define SCAN_CL 128
#define SCAN_W  128
#define SCAN_C  (SEQ_L / SCAN_CL)   // 16

typedef __attribute__((ext_vector_type(8))) short short8;
typedef __attribute__((ext_vector_type(4))) float f32x4;
typedef unsigned int u32;
typedef unsigned short u16;

__device__ __forceinline__ u16 bf_hi(float x) {            // truncate fp32 -> bf16
  return (u16)(__float_as_uint(x) >> 16);
}
__device__ __forceinline__ float bf_f(u16 h) {
  return __uint_as_float(((u32)h) << 16);
}
__device__ __forceinline__ void gload16(const void* g, void* l) {
  __builtin_amdgcn_global_load_lds((const __attribute__((address_space(1))) u32*)g,
                                   (__attribute__((address_space(3))) u32*)l, 16, 0, 0);
}

#define VMCNT0() asm volatile("s_waitcnt vmcnt(0)" ::: "memory")
#define VMCNT2() asm volatile("s_waitcnt vmcnt(2)" ::: "memory")
#define VMCNT6() asm volatile("s_waitcnt vmcnt(6)" ::: "memory")
#define BARRIER()                                    \
  {                                                  \
    asm volatile("" ::: "memory");                   \
    __builtin_amdgcn_s_barrier();                    \
    asm volatile("" ::: "memory");                   \
  }

// --------------------------------------------- prep: LN-in split + weight split
// blockIdx.x < MROWS        : ln_split row
// blockIdx.x >= MROWS       : weight-split chunk (W_in then W_out)
__global__ __launch_bounds__(256) void prep_kernel(
    const float* __restrict__ x, const float* __restrict__ g,
    const float* __restrict__ b, u16* __restrict__ y0, u16* __restrict__ y1,
    const float* __restrict__ W1, u16* __restrict__ a0, u16* __restrict__ a1,
    int n1, const float* __restrict__ W2, u16* __restrict__ c0,
    u16* __restrict__ c1, int n2)
{
  const int bx = blockIdx.x;
  const int t = threadIdx.x;
  if (bx >= MROWS) {                      // ---- weight split ----
    int i = (bx - MROWS) * 256 + t;
    if (i < n1) {
      float v = W1[i];
      u16 h0 = bf_hi(v);
      a0[i] = h0; a1[i] = bf_hi(v - bf_f(h0));
    } else if (i < n1 + n2) {
      int j = i - n1;
      float v = W2[j];
      u16 h0 = bf_hi(v);
      c0[j] = h0; c1[j] = bf_hi(v - bf_f(h0));
    }
    return;
  }
  // ---- LayerNorm-in -> 2-term bf16 planes ----
  const int row = bx;
  float4 v = reinterpret_cast<const float4*>(x + (size_t)row * D_MODEL)[t];
  float s  = v.x + v.y + v.z + v.w;
  float s2 = v.x * v.x + v.y * v.y + v.z * v.z + v.w * v.w;
  #pragma unroll
  for (int o = 32; o > 0; o >>= 1) {
    s  += __shfl_down(s, o);
    s2 += __shfl_down(s2, o);
  }
  __shared__ float ls[4], ls2[4];
  const int wid = t >> 6, lid = t & 63;
  if (lid == 0) { ls[wid] = s; ls2[wid] = s2; }
  __syncthreads();
  if (t == 0) {
    ls[0]  = ls[0] + ls[1] + ls[2] + ls[3];
    ls2[0] = ls2[0] + ls2[1] + ls2[2] + ls2[3];
  }
  __syncthreads();
  const float mean = ls[0] * (1.0f / D_MODEL);
  const float var  = ls2[0] * (1.0f / D_MODEL) - mean * mean;
  const float rstd = rsqrtf(var + 1e-5f);
  float4 gv = reinterpret_cast<const float4*>(g)[t];
  float4 bv = reinterpret_cast<const float4*>(b)[t];
  float o[4];
  o[0] = (v.x - mean) * rstd * gv.x + bv.x;
  o[1] = (v.y - mean) * rstd * gv.y + bv.y;
  o[2] = (v.z - mean) * rstd * gv.z + bv.z;
  o[3] = (v.w - mean) * rstd * gv.w + bv.w;
  ushort4 h0, h1;
  u16 a, c;
  a = bf_hi(o[0]); c = bf_hi(o[0] - bf_f(a)); h0.x = a; h1.x = c;
  a = bf_hi(o[1]); c = bf_hi(o[1] - bf_f(a)); h0.y = a; h1.y = c;
  a = bf_hi(o[2]); c = bf_hi(o[2] - bf_f(a)); h0.z = a; h1.z = c;
  a = bf_hi(o[3]); c = bf_hi(o[3] - bf_f(a)); h0.w = a; h1.w = c;
  reinterpret_cast<ushort4*>(y0 + (size_t)row * D_MODEL)[t] = h0;
  reinterpret_cast<ushort4*>(y1 + (size_t)row * D_MODEL)[t] = h1;
}

// LN over clip(pa+pb) — fuses GEMM2's split-K reduction + clip epilogue.
__global__ __launch_bounds__(256) void ln_sum_kernel(
    const float* __restrict__ xa, const float* __restrict__ xb,
    const float* __restrict__ g, const float* __restrict__ b,
    float* __restrict__ y)
{
  const int row = blockIdx.x;
  const int t = threadIdx.x;
  float4 va = reinterpret_cast<const float4*>(xa + (size_t)row * D_MODEL)[t];
  float4 vb = reinterpret_cast<const float4*>(xb + (size_t)row * D_MODEL)[t];
  float4 v;
  v.x = fminf(fmaxf(va.x + vb.x, -5.0f), 5.0f);
  v.y = fminf(fmaxf(va.y + vb.y, -5.0f), 5.0f);
  v.z = fminf(fmaxf(va.z + vb.z, -5.0f), 5.0f);
  v.w = fminf(fmaxf(va.w + vb.w, -5.0f), 5.0f);
  float s  = v.x + v.y + v.z + v.w;
  float s2 = v.x * v.x + v.y * v.y + v.z * v.z + v.w * v.w;
  #pragma unroll
  for (int o = 32; o > 0; o >>= 1) {
    s  += __shfl_down(s, o);
    s2 += __shfl_down(s2, o);
  }
  __shared__ float ls[4], ls2[4];
  const int wid = t >> 6, lid = t & 63;
  if (lid == 0) { ls[wid] = s; ls2[wid] = s2; }
  __syncthreads();
  if (t == 0) {
    ls[0]  = ls[0] + ls[1] + ls[2] + ls[3];
    ls2[0] = ls2[0] + ls2[1] + ls2[2] + ls2[3];
  }
  __syncthreads();
  const float mean = ls[0] * (1.0f / D_MODEL);
  const float var  = ls2[0] * (1.0f / D_MODEL) - mean * mean;
  const float rstd = rsqrtf(var + 1e-5f);
  float4 gv = reinterpret_cast<const float4*>(g)[t];
  float4 bv = reinterpret_cast<const float4*>(b)[t];
  float4 o;
  o.x = (v.x - mean) * rstd * gv.x + bv.x;
  o.y = (v.y - mean) * rstd * gv.y + bv.y;
  o.z = (v.z - mean) * rstd * gv.z + bv.z;
  o.w = (v.w - mean) * rstd * gv.w + bv.w;
  reinterpret_cast<float4*>(y + (size_t)row * D_MODEL)[t] = o;
}

// ---------------------------------------------------------------- GEMM
// 256x256 tile, 8 waves (2M x 4N, per-wave 128x64), BK=64 (1-combo) /
// BK=32 packed-planes (3-combo).  MINIMAL-SYNC schedule: 2 barriers +
// 2 counted vmcnt per K-tile, MFMA clusters of 32/48.  Reads(k) and
// stage-writes(k+1) hit different LDS buffers, so no intra-tile fences
// are needed beyond the two group-completion points.
//
// Stage groups per thread: G1 = Aalpha(2) + B-both-halves(4) = 6 loads
// (everything phase A of the NEXT tile reads), G2 = Abeta(2) (what
// phase B reads).  Waits:
//   phase-A end: vmcnt(6)  -> G2(k) resident   (leaves G1(k+1) in flight)
//   phase-B end: vmcnt(2)  -> G1(k+1) resident (leaves G2(k+1) in flight)
// Compiler handles ds_read->MFMA lgkmcnt fine-grained (no manual fences),
// so frag reads pipeline under the MFMA clusters.
#define MFMA(a, b, c) __builtin_amdgcn_mfma_f32_16x16x32_bf16(a, b, c, 0, 0, 0)
#define LD8(base, rb, c) \
  (*reinterpret_cast<const short8*>((base) + (rb) + ((c) << 3)))

template<bool THREE>
__device__ __forceinline__ void gemm_body(
    const u16* __restrict__ A0, const u16* __restrict__ A1,
    const u16* __restrict__ B0, const u16* __restrict__ B1,
    float* __restrict__ outp, int ld, int K, int Kld, int koff,
    int m0, int n0, int doclip, u16* sm)
{
  const int t = threadIdx.x;
  const int w = t >> 6, l = t & 63;
  const int wr = w >> 2, wc = w & 3;          // 2M x 4N waves
  const int q = l >> 4, m16 = l & 15;
  constexpr int KSTEP = THREE ? 32 : 64;
  const int NK = K / KSTEP;

  // staging lane geometry: one gload = 8 rows x 128B, lane l covers
  // row l>>3, physical chunk l&7; logical chunk = (l&7) ^ (row&7).
  const int arow = l >> 3, ac = l & 7;
  const int lc = ac ^ arow;
  const int coff = THREE ? ((lc & 3) << 3) : (lc << 3);
  const u16* const Asrc = (THREE && (lc & 4)) ? A1 : A0;
  const u16* const Bsrc = (THREE && (lc & 4)) ? B1 : B0;

  auto stageA = [&](int kt, int half) {       // half0: rows {0-63,128-191}
    const int kk = kt * KSTEP + koff + coff;
    u16* dbuf = sm + (size_t)(kt & 1) * 32768;
    #pragma unroll
    for (int j = 0; j < 2; j++) {
      const int gi = (j * 8 + w) * 8 + arow;
      const int r = ((gi & 63) | ((gi >> 6) << 7)) + half * 64;
      gload16(Asrc + (size_t)(m0 + r) * Kld + kk, dbuf + (r & ~7) * 64);
    }
  };
  auto stageB = [&](int kt, int half) {       // half0: rows bit5==0
    const int kk = kt * KSTEP + koff + coff;
    u16* dbuf = sm + (size_t)(kt & 1) * 32768 + 16384;
    #pragma unroll
    for (int j = 0; j < 2; j++) {
      const int gi = (j * 8 + w) * 8 + arow;
      const int r = ((gi & 31) | ((gi >> 5) << 6)) + half * 32;
      gload16(Bsrc + (size_t)(n0 + r) * Kld + kk, dbuf + (r & ~7) * 64);
    }
  };

  f32x4 acc[8][4];
  #pragma unroll
  for (int i = 0; i < 8; i++)
    #pragma unroll
    for (int j = 0; j < 4; j++) acc[i][j] = (f32x4)(0.0f);

  // prologue: G1(0) then G2(0); vmcnt(2) -> G1(0) resident, G2(0) flying
  stageA(0, 0); stageB(0, 0); stageB(0, 1);   // G1(0)
  stageA(0, 1);                               // G2(0)
  VMCNT2();
  BARRIER();

  short8 af[4][2], bf[4][2];

  for (int k = 0; k < NK; ++k) {
    const u16* sA = sm + (size_t)(k & 1) * 32768;
    const u16* sB = sA + 16384;
    const bool pf = (k + 1 < NK);

    // ================= phase A: mh0 (rows wr*128 .. +64) =================
    if (pf) { stageA(k + 1, 0); stageB(k + 1, 0); stageB(k + 1, 1); }  // G1
    #pragma unroll
    for (int mt = 0; mt < 4; mt++) {
      const int r = wr * 128 + mt * 16 + m16, rb = r * 64, rx = r & 7;
      af[mt][0] = LD8(sA, rb, q ^ rx);
      af[mt][1] = LD8(sA, rb, (4 + q) ^ rx);
    }
    #pragma unroll
    for (int nt = 0; nt < 4; nt++) {
      const int r = wc * 64 + nt * 16 + m16, rb = r * 64, rx = r & 7;
      bf[nt][0] = LD8(sB, rb, q ^ rx);
      bf[nt][1] = LD8(sB, rb, (4 + q) ^ rx);
    }
    __builtin_amdgcn_s_setprio(1);
    #pragma unroll
    for (int mt = 0; mt < 4; mt++)
      #pragma unroll
      for (int nt = 0; nt < 4; nt++) {
        f32x4 c = acc[mt][nt];
        if (THREE) {
          c = MFMA(af[mt][0], bf[nt][0], c);
          c = MFMA(af[mt][0], bf[nt][1], c);
          c = MFMA(af[mt][1], bf[nt][0], c);
        } else {
          c = MFMA(af[mt][0], bf[nt][0], c);
          c = MFMA(af[mt][1], bf[nt][1], c);
        }
        acc[mt][nt] = c;
      }
    __builtin_amdgcn_s_setprio(0);
    if (pf) VMCNT6(); else VMCNT0();          // G2(k) resident
    BARRIER();

    // ================= phase B: mh1 (rows wr*128+64 .. +128) =============
    #pragma unroll
    for (int mt = 0; mt < 4; mt++) {
      const int r = wr * 128 + 64 + mt * 16 + m16, rb = r * 64, rx = r & 7;
      af[mt][0] = LD8(sA, rb, q ^ rx);
      af[mt][1] = LD8(sA, rb, (4 + q) ^ rx);
    }
    if (pf) stageA(k + 1, 1);                 // G2(k+1)
    __builtin_amdgcn_s_setprio(1);
    #pragma unroll
    for (int mt = 0; mt < 4; mt++)
      #pragma unroll
      for (int nt = 0; nt < 4; nt++) {
        f32x4 c = acc[4 + mt][nt];
        if (THREE) {
          c = MFMA(af[mt][0], bf[nt][0], c);
          c = MFMA(af[mt][0], bf[nt][1], c);
          c = MFMA(af[mt][1], bf[nt][0], c);
        } else {
          c = MFMA(af[mt][0], bf[nt][0], c);
          c = MFMA(af[mt][1], bf[nt][1], c);
        }
        acc[4 + mt][nt] = c;
      }
    __builtin_amdgcn_s_setprio(0);
    if (pf) {
      VMCNT2();                               // G1(k+1) resident
      BARRIER();
    }
  }

  // epilogue: C/D layout col=lane&15, row=(lane>>4)*4+reg; out pointer
  // pre-offset by block column (block never straddles the split).
  #pragma unroll
  for (int mt = 0; mt < 8; mt++) {
    #pragma unroll
    for (int nt = 0; nt < 4; nt++) {
      const int col = wc * 64 + nt * 16 + m16;
      #pragma unroll
      for (int r = 0; r < 4; r++) {
        const int row = m0 + wr * 128 + mt * 16 + q * 4 + r;
        float v = acc[mt][nt][r];
        if (doclip) v = fminf(fmaxf(v, -5.0f), 5.0f);
        outp[(size_t)row * ld + col] = v;
      }
    }
  }
}

// GEMM1: x_proj = clip(xn @ W_in^T); cols <1536 (x_ssm) 1-combo, rest 3-combo.
__global__ __launch_bounds__(512, 2) void gemm1_kernel(
    const u16* __restrict__ A0, const u16* __restrict__ A1,
    const u16* __restrict__ B0, const u16* __restrict__ B1,
    float* __restrict__ out0, float* __restrict__ out1)
{
  __shared__ u16 sm[2][32768];               // 128 KiB
  const int m0 = blockIdx.x * 256;
  const int nblk = (int)gridDim.y - 1 - (int)blockIdx.y;   // heavy-first
  const int n0 = nblk * 256;
  if (n0 >= D_INNER)
    gemm_body<true>(A0, A1, B0, B1, out1 + (n0 - D_INNER), D_INNER,
                    D_MODEL, D_MODEL, 0, m0, n0, 1, &sm[0][0]);
  else
    gemm_body<false>(A0, A1, B0, B1, out0 + n0, D_INNER,
                     D_MODEL, D_MODEL, 0, m0, n0, 1, &sm[0][0]);
}

// GEMM2: out_pre partials = prod @ W_out^T, split-K=2 (unclipped fp32
// partials into outA/outB; ln_sum does clip(pa+pb) + LN).
__global__ __launch_bounds__(512, 2) void gemm2_kernel(
    const u16* __restrict__ P0, const u16* __restrict__ P1,
    const u16* __restrict__ V0, const u16* __restrict__ V1,
    float* __restrict__ outA, float* __restrict__ outB)
{
  __shared__ u16 sm[2][32768];
  const int m0 = blockIdx.x * 256;
  const int by = (int)blockIdx.y;
  const int kslice = by >> 2;
  const int n0 = (by & 3) * 256;
  float* o = (kslice ? outB : outA) + n0;
  gemm_body<true>(P0, P1, V0, V1, o, D_MODEL, 768, 1536, kslice * 768,
                  m0, n0, 0, &sm[0][0]);
}

// --------------------------------------------------------------- SSM scan
__global__ __launch_bounds__(256) void scan_kernel(
    const float* __restrict__ xssm, const float* __restrict__ gate,
    const float* __restrict__ A_log, const float* __restrict__ Bv,
    const float* __restrict__ Cv, u16* __restrict__ P0, u16* __restrict__ P1)
{
  const int gid = blockIdx.x * 256 + threadIdx.x;       // 0 .. 98303
  const int chunk = gid / (BATCH * D_INNER);            // 0..15
  const int rem = gid - chunk * (BATCH * D_INNER);
  const int b = rem / D_INNER;
  const int i = rem - b * D_INNER;

  float dec[D_STATE], bb[D_STATE], cc[D_STATE], h[D_STATE];
  #pragma unroll
  for (int s = 0; s < D_STATE; s++) {
    float al = A_log[i * D_STATE + s];
    al = fminf(fmaxf(al, -5.0f), 0.0f);
    float a = -__expf(al);
    a = fminf(fmaxf(a, -2.0f), -0.01f);
    dec[s] = a * 0.9f;
    bb[s]  = Bv[i * D_STATE + s] * 0.1f;
    cc[s]  = Cv[i * D_STATE + s];
    h[s]   = 0.0f;
  }

  const size_t base = (size_t)b * SEQ_L * D_INNER + i;
  const int tmain = chunk * SCAN_CL;
  const int tw = (tmain >= SCAN_W) ? (tmain - SCAN_W) : 0;

  for (int t0 = tw; t0 < tmain; t0 += 16) {
    float xv[16];
    #pragma unroll
    for (int j = 0; j < 16; j++)
      xv[j] = xssm[base + (size_t)(t0 + j) * D_INNER];
    #pragma unroll
    for (int j = 0; j < 16; j++) {
      const float x = xv[j];
      #pragma unroll
      for (int s = 0; s < D_STATE; s++) {
        h[s] = fmaf(h[s], dec[s], x * bb[s]);
        h[s] = fminf(fmaxf(h[s], -5.0f), 5.0f);
      }
    }
  }

  float xf[8], gf[8];
  #pragma unroll
  for (int j = 0; j < 8; j++) {
    xf[j] = xssm[base + (size_t)(tmain + j) * D_INNER];
    gf[j] = gate[base + (size_t)(tmain + j) * D_INNER];
  }
  for (int t0 = tmain; t0 < tmain + SCAN_CL; t0 += 8) {
    float xn[8], gn[8];
    if (t0 + 8 < tmain + SCAN_CL) {
      #pragma unroll
      for (int j = 0; j < 8; j++) {
        xn[j] = xssm[base + (size_t)(t0 + 8 + j) * D_INNER];
        gn[j] = gate[base + (size_t)(t0 + 8 + j) * D_INNER];
      }
    }
    #pragma unroll
    for (int j = 0; j < 8; j++) {
      const float x = xf[j];
      float y = 0.0f;
      #pragma unroll
      for (int s = 0; s < D_STATE; s++) {
        h[s] = fmaf(h[s], dec[s], x * bb[s]);
        h[s] = fminf(fmaxf(h[s], -5.0f), 5.0f);
        y = fmaf(h[s], cc[s], y);
      }
      y = fminf(fmaxf(y, -5.0f), 5.0f);
      const float e  = __expf(2.0f * gf[j]);
      const float th = __fdividef(e - 1.0f, e + 1.0f);
      const float p = y * th;
      const u16 h0 = bf_hi(p);
      const u16 h1 = bf_hi(p - bf_f(h0));
      P0[base + (size_t)(t0 + j) * D_INNER] = h0;
      P1[base + (size_t)(t0 + j) * D_INNER] = h1;
    }
    #pragma unroll
    for (int j = 0; j < 8; j++) { xf[j] = xn[j]; gf[j] = gn[j]; }
  }
}

// ---------------------------------------------------------------- launcher
extern "C" void kernel_launch(void* const* d_in, const int* in_sizes, int n_in,
                              void* d_out, int out_size, void* d_ws, size_t ws_size,
                              hipStream_t stream)
{
  const float* x        = (const float*)d_in[0];
  const float* W_in     = (const float*)d_in[1];
  const float* W_out    = (const float*)d_in[2];
  const float* A_log    = (const float*)d_in[3];
  const float* Bmat     = (const float*)d_in[4];
  const float* Cmat     = (const float*)d_in[5];
  const float* ln_in_g  = (const float*)d_in[6];
  const float* ln_in_b  = (const float*)d_in[7];
  const float* ln_out_g = (const float*)d_in[8];
  const float* ln_out_b = (const float*)d_in[9];
  float* out = (float*)d_out;

  // workspace layout (bytes): see round-2 comment; unchanged.
  char* ws = (char*)d_ws;
  float* xssm = (float*)(ws);
  float* gate = (float*)(ws + 50331648);
  u16* xn0 = (u16*)(ws + 100663296);
  u16* xn1 = (u16*)(ws + 117440512);
  u16* B0  = (u16*)(ws + 134217728);
  u16* B1  = (u16*)(ws + 140509184);
  u16* V0  = (u16*)(ws + 153092096);
  u16* V1  = (u16*)(ws + 156237824);
  u16* P0  = (u16*)(ws + 100663296);
  u16* P1  = P0 + (size_t)MROWS * D_INNER;
  float* outA = xssm;
  float* outB = gate;

  // 0+1) fused: LN-in split rows + weight splits
  {
    const int n1 = 2 * D_INNER * D_MODEL;      // W_in
    const int n2 = D_MODEL * D_INNER;          // W_out
    const int wblocks = (n1 + n2 + 255) / 256;
    prep_kernel<<<MROWS + wblocks, 256, 0, stream>>>(
        x, ln_in_g, ln_in_b, xn0, xn1, W_in, B0, B1, n1, W_out, V0, V1, n2);
  }

  // 2) x_proj = clip(xn @ W_in^T), split-store xssm/gate.
  gemm1_kernel<<<dim3(MROWS / 256, (2 * D_INNER) / 256), 512, 0, stream>>>(
      xn0, xn1, B0, B1, xssm, gate);

  // 3) chunked SSM scan -> prod as 2-term bf16
  scan_kernel<<<(BATCH * D_INNER * SCAN_C) / 256, 256, 0, stream>>>(
      xssm, gate, A_log, Bmat, Cmat, P0, P1);

  // 4) out_pre = prod @ W_out^T, split-K=2 -> fp32 partials outA/outB
  gemm2_kernel<<<dim3(MROWS / 256, 2 * (D_MODEL / 256)), 512, 0, stream>>>(
      P0, P1, V0, V1, outA, outB);

  // 5) LayerNorm over clip(outA + outB) -> d_out
  ln_sum_kernel<<<MROWS, 256, 0, stream>>>(outA, outB, ln_out_g, ln_out_b, out);
}